// Round 1
// baseline (188.027 us; speedup 1.0000x reference)
//
#include <hip/hip_runtime.h>

#define FEAT_DIM 256
#define K_NEIGH  32
#define NROWS    20480   // B*S = 2048*10
#define NOUT     1024    // CLIPS*DIM = 8*128

typedef __attribute__((ext_vector_type(8))) short bf16x8;
typedef __attribute__((ext_vector_type(4))) float f32x4;

// round-to-nearest-even fp32 -> bf16 (no NaN handling needed; data is finite)
__device__ __forceinline__ unsigned short f2bf(float f) {
    unsigned int u = __builtin_bit_cast(unsigned int, f);
    u += 0x7fffu + ((u >> 16) & 1u);
    return (unsigned short)(u >> 16);
}

// ---- Kernel 1: local_weight [1024,256] fp32 -> bf16 -------------------------
__global__ __launch_bounds__(256) void wcvt_kernel(const float* __restrict__ w,
                                                   unsigned short* __restrict__ wb) {
    int i = (blockIdx.x * 256 + threadIdx.x) * 4;
    float4 v = *(const float4*)(w + i);
    ushort4 o;
    o.x = f2bf(v.x); o.y = f2bf(v.y); o.z = f2bf(v.z); o.w = f2bf(v.w);
    *(ushort4*)(wb + i) = o;
}

// ---- Kernel 2: neighbor mean aggregation -> bf16 feat [NROWS,256] -----------
__global__ __launch_bounds__(256) void agg_kernel(const int* __restrict__ nodes,
                                                  const int* __restrict__ adj,
                                                  const float* __restrict__ features,
                                                  unsigned short* __restrict__ feat) {
    int row = blockIdx.x;        // one block per output row
    int t = threadIdx.x;         // feature dim 0..255
    int node = nodes[row];       // uniform per block -> scalar load
    const int* arow = adj + (long)node * K_NEIGH;
    float acc = 0.f;
    #pragma unroll
    for (int k = 0; k < K_NEIGH; ++k) {
        long nb = arow[k];                         // uniform
        acc += features[nb * FEAT_DIM + t];        // coalesced 1KB/row
    }
    feat[(long)row * FEAT_DIM + t] = f2bf(acc * (1.0f / K_NEIGH));
}

// ---- Kernel 3: C[M,1024] = relu(feat[M,256] x W[1024,256]^T), MFMA bf16 -----
// block tile 64M x 64N; 4 waves stacked on M, each wave 16M x 64N.
__global__ __launch_bounds__(256) void gemm_kernel(const unsigned short* __restrict__ A,
                                                   const unsigned short* __restrict__ Bw,
                                                   float* __restrict__ C) {
    int wave = threadIdx.x >> 6;
    int lane = threadIdx.x & 63;
    int m0 = blockIdx.x * 64 + wave * 16;
    int n0 = blockIdx.y * 64;
    int lr = lane & 15;            // row (A) / col (B) within fragment
    int lk = (lane >> 4) * 8;      // k-offset within 32

    const short* a_ptr = (const short*)A + (long)(m0 + lr) * FEAT_DIM + lk;
    const short* b_ptr = (const short*)Bw + (long)(n0 + lr) * FEAT_DIM + lk;

    f32x4 acc[4] = {f32x4{0,0,0,0}, f32x4{0,0,0,0}, f32x4{0,0,0,0}, f32x4{0,0,0,0}};

    #pragma unroll
    for (int kb = 0; kb < FEAT_DIM; kb += 32) {
        bf16x8 a = *(const bf16x8*)(a_ptr + kb);
        #pragma unroll
        for (int t = 0; t < 4; ++t) {
            bf16x8 b = *(const bf16x8*)(b_ptr + (long)t * 16 * FEAT_DIM + kb);
            acc[t] = __builtin_amdgcn_mfma_f32_16x16x32_bf16(a, b, acc[t], 0, 0, 0);
        }
    }

    // C/D layout (verified m89/m91): col = lane&15, row = (lane>>4)*4 + reg
    int crow = m0 + (lane >> 4) * 4;
    int ccol = n0 + lr;
    #pragma unroll
    for (int t = 0; t < 4; ++t) {
        #pragma unroll
        for (int r = 0; r < 4; ++r) {
            float v = acc[t][r];
            C[(long)(crow + r) * NOUT + ccol + t * 16] = v > 0.f ? v : 0.f;
        }
    }
}

extern "C" void kernel_launch(void* const* d_in, const int* in_sizes, int n_in,
                              void* d_out, int out_size, void* d_ws, size_t ws_size,
                              hipStream_t stream) {
    const int*   nodes    = (const int*)d_in[0];
    const int*   adj      = (const int*)d_in[1];
    const float* features = (const float*)d_in[2];
    const float* lw       = (const float*)d_in[3];
    float*       out      = (float*)d_out;

    // workspace: feat bf16 [NROWS,256] then W bf16 [1024,256]  (~11 MB total)
    unsigned short* feat = (unsigned short*)d_ws;
    unsigned short* wb   = feat + (size_t)NROWS * FEAT_DIM;

    wcvt_kernel<<<(NOUT * FEAT_DIM) / (256 * 4), 256, 0, stream>>>(lw, wb);
    agg_kernel<<<NROWS, 256, 0, stream>>>(nodes, adj, features, feat);
    gemm_kernel<<<dim3(NROWS / 64, NOUT / 64), 256, 0, stream>>>(feat, wb, out);
}

// Round 2
// 86.965 us; speedup vs baseline: 2.1621x; 2.1621x over previous
//
#include <hip/hip_runtime.h>

#define FEAT_DIM 256
#define K_NEIGH  32
#define NROWS    20480   // B*S = 2048*10
#define NOUT     1024    // CLIPS*DIM = 8*128
#define NUM_NODES 50000

typedef __attribute__((ext_vector_type(8))) short bf16x8;
typedef __attribute__((ext_vector_type(4))) float f32x4;

__device__ __forceinline__ unsigned short f2bf(float f) {
    unsigned int u = __builtin_bit_cast(unsigned int, f);
    u += 0x7fffu + ((u >> 16) & 1u);
    return (unsigned short)(u >> 16);
}
__device__ __forceinline__ float bf2f(unsigned short h) {
    unsigned int u = ((unsigned int)h) << 16;
    return __builtin_bit_cast(float, u);
}
__device__ __forceinline__ void gload16(const void* g, void* l) {
    __builtin_amdgcn_global_load_lds(
        (const __attribute__((address_space(1))) unsigned int*)g,
        (__attribute__((address_space(3))) unsigned int*)l, 16, 0, 0);
}

// ---- local_weight [1024,256] fp32 -> bf16 -----------------------------------
__global__ __launch_bounds__(256) void wcvt_kernel(const float* __restrict__ w,
                                                   unsigned short* __restrict__ wb) {
    int i = (blockIdx.x * 256 + threadIdx.x) * 4;
    float4 v = *(const float4*)(w + i);
    ushort4 o;
    o.x = f2bf(v.x); o.y = f2bf(v.y); o.z = f2bf(v.z); o.w = f2bf(v.w);
    *(ushort4*)(wb + i) = o;
}

// ---- features [50000,256] fp32 -> bf16 --------------------------------------
__global__ __launch_bounds__(256) void fcvt_kernel(const float* __restrict__ f,
                                                   unsigned short* __restrict__ fb) {
    long i = (long)(blockIdx.x * 256 + threadIdx.x) * 8;
    float4 v0 = *(const float4*)(f + i);
    float4 v1 = *(const float4*)(f + i + 4);
    ushort4 o0, o1;
    o0.x = f2bf(v0.x); o0.y = f2bf(v0.y); o0.z = f2bf(v0.z); o0.w = f2bf(v0.w);
    o1.x = f2bf(v1.x); o1.y = f2bf(v1.y); o1.z = f2bf(v1.z); o1.w = f2bf(v1.w);
    *(ushort4*)(fb + i) = o0;
    *(ushort4*)(fb + i + 4) = o1;
}

// ---- agg from bf16 features: 2 rows per 256-thread block --------------------
__global__ __launch_bounds__(256) void agg_bf_kernel(const int* __restrict__ nodes,
                                                     const int* __restrict__ adj,
                                                     const unsigned short* __restrict__ fb,
                                                     unsigned short* __restrict__ feat) {
    int half = threadIdx.x >> 7;        // waves 0-1 -> row a, waves 2-3 -> row b
    int t = threadIdx.x & 127;          // dim-pair index
    int row = blockIdx.x * 2 + half;
    int node = nodes[row];
    const int* arow = adj + (long)node * K_NEIGH;
    float a0 = 0.f, a1 = 0.f;
    #pragma unroll
    for (int k = 0; k < K_NEIGH; ++k) {
        long nb = arow[k];
        unsigned int v = *(const unsigned int*)(fb + nb * FEAT_DIM + 2 * t);
        a0 += bf2f((unsigned short)(v & 0xffffu));
        a1 += bf2f((unsigned short)(v >> 16));
    }
    ushort2 o;
    o.x = f2bf(a0 * (1.0f / K_NEIGH));
    o.y = f2bf(a1 * (1.0f / K_NEIGH));
    *(ushort2*)(feat + (long)row * FEAT_DIM + 2 * t) = o;
}

// ---- agg from fp32 features (ws fallback) -----------------------------------
__global__ __launch_bounds__(256) void agg_f32_kernel(const int* __restrict__ nodes,
                                                      const int* __restrict__ adj,
                                                      const float* __restrict__ features,
                                                      unsigned short* __restrict__ feat) {
    int row = blockIdx.x;
    int t = threadIdx.x;
    int node = nodes[row];
    const int* arow = adj + (long)node * K_NEIGH;
    float acc = 0.f;
    #pragma unroll
    for (int k = 0; k < K_NEIGH; ++k) {
        long nb = arow[k];
        acc += features[nb * FEAT_DIM + t];
    }
    feat[(long)row * FEAT_DIM + t] = f2bf(acc * (1.0f / K_NEIGH));
}

// ---- GEMM: C[M,1024] = relu(feat[M,256] x W[1024,256]^T), m97 structure -----
// 128x128 block tile, BK=32, 4 waves in 2x2, each 64x64 (4x4 fragments).
__global__ __launch_bounds__(256) void gemm_kernel(const unsigned short* __restrict__ A,
                                                   const unsigned short* __restrict__ Bw,
                                                   float* __restrict__ C) {
    __shared__ short As[128 * 32];   // 8 KB, row-major [row][k]
    __shared__ short Bs[128 * 32];   // 8 KB

    int t = threadIdx.x;
    int wave = t >> 6, lane = t & 63;
    int wm = wave >> 1, wn = wave & 1;
    int m0 = blockIdx.x * 128, n0 = blockIdx.y * 128;
    int lr = lane & 15;
    int lk = (lane >> 4) * 8;

    // staging: thread t covers row t/4, 8-short segment t%4 (16B per lane)
    int srow = t >> 2;
    int sseg = (t & 3) * 8;
    const short* Ag = (const short*)A + (long)(m0 + srow) * FEAT_DIM + sseg;
    const short* Bg = (const short*)Bw + (long)(n0 + srow) * FEAT_DIM + sseg;
    short* Al = As + t * 8;          // byte offset = wave base + lane*16
    short* Bl = Bs + t * 8;

    f32x4 acc[4][4] = {};

    for (int kb = 0; kb < FEAT_DIM; kb += 32) {
        if (kb) __syncthreads();                 // LDS reuse guard
        gload16(Ag + kb, Al);
        gload16(Ag + 64 * FEAT_DIM + kb, Al + 64 * 32);
        gload16(Bg + kb, Bl);
        gload16(Bg + 64 * FEAT_DIM + kb, Bl + 64 * 32);
        __syncthreads();                          // compiler drains vmcnt first

        bf16x8 a[4], b[4];
        #pragma unroll
        for (int i = 0; i < 4; ++i)
            a[i] = *(const bf16x8*)(As + (wm * 64 + i * 16 + lr) * 32 + lk);
        #pragma unroll
        for (int j = 0; j < 4; ++j)
            b[j] = *(const bf16x8*)(Bs + (wn * 64 + j * 16 + lr) * 32 + lk);
        #pragma unroll
        for (int i = 0; i < 4; ++i)
            #pragma unroll
            for (int j = 0; j < 4; ++j)
                acc[i][j] = __builtin_amdgcn_mfma_f32_16x16x32_bf16(a[i], b[j], acc[i][j], 0, 0, 0);
    }

    // C/D layout: col = lane&15, row = (lane>>4)*4 + reg  (verified in R0)
    int crow0 = m0 + wm * 64 + (lane >> 4) * 4;
    int ccol0 = n0 + wn * 64 + lr;
    #pragma unroll
    for (int i = 0; i < 4; ++i)
        #pragma unroll
        for (int j = 0; j < 4; ++j)
            #pragma unroll
            for (int r = 0; r < 4; ++r) {
                float v = acc[i][j][r];
                C[(long)(crow0 + i * 16 + r) * NOUT + ccol0 + j * 16] = v > 0.f ? v : 0.f;
            }
}

extern "C" void kernel_launch(void* const* d_in, const int* in_sizes, int n_in,
                              void* d_out, int out_size, void* d_ws, size_t ws_size,
                              hipStream_t stream) {
    const int*   nodes    = (const int*)d_in[0];
    const int*   adj      = (const int*)d_in[1];
    const float* features = (const float*)d_in[2];
    const float* lw       = (const float*)d_in[3];
    float*       out      = (float*)d_out;

    const size_t fbf_elems  = (size_t)NUM_NODES * FEAT_DIM;   // 12.8M shorts
    const size_t feat_elems = (size_t)NROWS * FEAT_DIM;       // 5.24M shorts
    const size_t need = (fbf_elems + feat_elems + (size_t)NOUT * FEAT_DIM) * 2;

    if (ws_size >= need) {
        unsigned short* fbf  = (unsigned short*)d_ws;
        unsigned short* feat = fbf + fbf_elems;
        unsigned short* wb   = feat + feat_elems;

        wcvt_kernel<<<(NOUT * FEAT_DIM) / (256 * 4), 256, 0, stream>>>(lw, wb);
        fcvt_kernel<<<(int)(fbf_elems / (256 * 8)), 256, 0, stream>>>(features, fbf);
        agg_bf_kernel<<<NROWS / 2, 256, 0, stream>>>(nodes, adj, fbf, feat);
        gemm_kernel<<<dim3(NROWS / 128, NOUT / 128), 256, 0, stream>>>(feat, wb, out);
    } else {
        unsigned short* feat = (unsigned short*)d_ws;
        unsigned short* wb   = feat + feat_elems;

        wcvt_kernel<<<(NOUT * FEAT_DIM) / (256 * 4), 256, 0, stream>>>(lw, wb);
        agg_f32_kernel<<<NROWS, 256, 0, stream>>>(nodes, adj, features, feat);
        gemm_kernel<<<dim3(NROWS / 128, NOUT / 128), 256, 0, stream>>>(feat, wb, out);
    }
}

// Round 3
// 78.266 us; speedup vs baseline: 2.4024x; 1.1112x over previous
//
#include <hip/hip_runtime.h>

#define FEAT_DIM 256
#define K_NEIGH  32
#define NROWS    20480   // B*S = 2048*10
#define NOUT     1024    // CLIPS*DIM = 8*128
#define NUM_NODES 50000
#define SLICE_DIM 32     // dims per XCD slice
#define NSLICE    8

typedef __attribute__((ext_vector_type(8))) short bf16x8;
typedef __attribute__((ext_vector_type(4))) float f32x4;

__device__ __forceinline__ unsigned short f2bf(float f) {
    unsigned int u = __builtin_bit_cast(unsigned int, f);
    u += 0x7fffu + ((u >> 16) & 1u);
    return (unsigned short)(u >> 16);
}
__device__ __forceinline__ float bf2f(unsigned short h) {
    unsigned int u = ((unsigned int)h) << 16;
    return __builtin_bit_cast(float, u);
}
__device__ __forceinline__ void gload16(const void* g, void* l) {
    __builtin_amdgcn_global_load_lds(
        (const __attribute__((address_space(1))) unsigned int*)g,
        (__attribute__((address_space(3))) unsigned int*)l, 16, 0, 0);
}

// ---- local_weight [1024,256] fp32 -> bf16 -----------------------------------
__global__ __launch_bounds__(256) void wcvt_kernel(const float* __restrict__ w,
                                                   unsigned short* __restrict__ wb) {
    int i = (blockIdx.x * 256 + threadIdx.x) * 4;
    float4 v = *(const float4*)(w + i);
    ushort4 o;
    o.x = f2bf(v.x); o.y = f2bf(v.y); o.z = f2bf(v.z); o.w = f2bf(v.w);
    *(ushort4*)(wb + i) = o;
}

// ---- features [50000,256] fp32 -> bf16, XCD-sliced layout fb[8][50000][32] --
__global__ __launch_bounds__(256) void fcvt_sliced(const float* __restrict__ f,
                                                   unsigned short* __restrict__ fb) {
    int t = threadIdx.x;
    int node = blockIdx.x * 16 + (t >> 4);
    int part = t & 15;              // 16 dims per thread
    int slice = part >> 1, half = part & 1;
    const float* src = f + (long)node * FEAT_DIM + part * 16;
    unsigned short o[16];
    #pragma unroll
    for (int j = 0; j < 16; j += 4) {
        float4 v = *(const float4*)(src + j);
        o[j] = f2bf(v.x); o[j+1] = f2bf(v.y); o[j+2] = f2bf(v.z); o[j+3] = f2bf(v.w);
    }
    unsigned short* dst = fb + ((long)slice * NUM_NODES + node) * SLICE_DIM + half * 16;
    *(bf16x8*)dst = *(const bf16x8*)o;
    *(bf16x8*)(dst + 8) = *(const bf16x8*)(o + 8);
}

// ---- agg, XCD-sliced: slice s blocks land on XCD s (blockIdx % 8 heuristic) -
// block: 256 thr = 4 lanes/(row,slice) x 64 rows; each lane: 8 dims over 32 nbrs
__global__ __launch_bounds__(256) void agg_sliced(const int* __restrict__ nodes,
                                                  const int* __restrict__ adj,
                                                  const unsigned short* __restrict__ fb,
                                                  unsigned short* __restrict__ feat) {
    int slice = blockIdx.x & 7;
    int chunk = blockIdx.x >> 3;
    int t = threadIdx.x;
    int row = chunk * 64 + (t >> 2);
    int d8 = (t & 3) * 8;           // dim offset within slice
    int node = nodes[row];
    const int* arow = adj + (long)node * K_NEIGH;
    int nbr[K_NEIGH];
    #pragma unroll
    for (int kk = 0; kk < K_NEIGH / 4; ++kk)
        *(int4*)(nbr + kk * 4) = ((const int4*)arow)[kk];

    const unsigned short* base = fb + (long)slice * NUM_NODES * SLICE_DIM + d8;
    float acc[8] = {};
    #pragma unroll
    for (int k = 0; k < K_NEIGH; ++k) {
        bf16x8 v = *(const bf16x8*)(base + (long)nbr[k] * SLICE_DIM);
        #pragma unroll
        for (int j = 0; j < 8; ++j) acc[j] += bf2f((unsigned short)v[j]);
    }
    unsigned short o[8];
    #pragma unroll
    for (int j = 0; j < 8; ++j) o[j] = f2bf(acc[j] * (1.0f / K_NEIGH));
    *(bf16x8*)(feat + (long)row * FEAT_DIM + slice * SLICE_DIM + d8) = *(const bf16x8*)o;
}

// ---- agg from fp32 features (ws fallback) -----------------------------------
__global__ __launch_bounds__(256) void agg_f32_kernel(const int* __restrict__ nodes,
                                                      const int* __restrict__ adj,
                                                      const float* __restrict__ features,
                                                      unsigned short* __restrict__ feat) {
    int row = blockIdx.x;
    int t = threadIdx.x;
    int node = nodes[row];
    const int* arow = adj + (long)node * K_NEIGH;
    float acc = 0.f;
    #pragma unroll
    for (int k = 0; k < K_NEIGH; ++k) {
        long nb = arow[k];
        acc += features[nb * FEAT_DIM + t];
    }
    feat[(long)row * FEAT_DIM + t] = f2bf(acc * (1.0f / K_NEIGH));
}

// ---- GEMM: C[M,1024] = relu(feat[M,256] x W[1024,256]^T), m97 structure -----
__global__ __launch_bounds__(256) void gemm_kernel(const unsigned short* __restrict__ A,
                                                   const unsigned short* __restrict__ Bw,
                                                   float* __restrict__ C) {
    __shared__ short As[128 * 32];
    __shared__ short Bs[128 * 32];

    int t = threadIdx.x;
    int wave = t >> 6, lane = t & 63;
    int wm = wave >> 1, wn = wave & 1;
    int m0 = blockIdx.x * 128, n0 = blockIdx.y * 128;
    int lr = lane & 15;
    int lk = (lane >> 4) * 8;

    int srow = t >> 2;
    int sseg = (t & 3) * 8;
    const short* Ag = (const short*)A + (long)(m0 + srow) * FEAT_DIM + sseg;
    const short* Bg = (const short*)Bw + (long)(n0 + srow) * FEAT_DIM + sseg;
    short* Al = As + t * 8;
    short* Bl = Bs + t * 8;

    f32x4 acc[4][4] = {};

    for (int kb = 0; kb < FEAT_DIM; kb += 32) {
        if (kb) __syncthreads();
        gload16(Ag + kb, Al);
        gload16(Ag + 64 * FEAT_DIM + kb, Al + 64 * 32);
        gload16(Bg + kb, Bl);
        gload16(Bg + 64 * FEAT_DIM + kb, Bl + 64 * 32);
        __syncthreads();

        bf16x8 a[4], b[4];
        #pragma unroll
        for (int i = 0; i < 4; ++i)
            a[i] = *(const bf16x8*)(As + (wm * 64 + i * 16 + lr) * 32 + lk);
        #pragma unroll
        for (int j = 0; j < 4; ++j)
            b[j] = *(const bf16x8*)(Bs + (wn * 64 + j * 16 + lr) * 32 + lk);
        #pragma unroll
        for (int i = 0; i < 4; ++i)
            #pragma unroll
            for (int j = 0; j < 4; ++j)
                acc[i][j] = __builtin_amdgcn_mfma_f32_16x16x32_bf16(a[i], b[j], acc[i][j], 0, 0, 0);
    }

    int crow0 = m0 + wm * 64 + (lane >> 4) * 4;
    int ccol0 = n0 + wn * 64 + lr;
    #pragma unroll
    for (int i = 0; i < 4; ++i)
        #pragma unroll
        for (int j = 0; j < 4; ++j)
            #pragma unroll
            for (int r = 0; r < 4; ++r) {
                float v = acc[i][j][r];
                C[(long)(crow0 + i * 16 + r) * NOUT + ccol0 + j * 16] = v > 0.f ? v : 0.f;
            }
}

extern "C" void kernel_launch(void* const* d_in, const int* in_sizes, int n_in,
                              void* d_out, int out_size, void* d_ws, size_t ws_size,
                              hipStream_t stream) {
    const int*   nodes    = (const int*)d_in[0];
    const int*   adj      = (const int*)d_in[1];
    const float* features = (const float*)d_in[2];
    const float* lw       = (const float*)d_in[3];
    float*       out      = (float*)d_out;

    const size_t fbf_elems  = (size_t)NUM_NODES * FEAT_DIM;
    const size_t feat_elems = (size_t)NROWS * FEAT_DIM;
    const size_t need = (fbf_elems + feat_elems + (size_t)NOUT * FEAT_DIM) * 2;

    if (ws_size >= need) {
        unsigned short* fbf  = (unsigned short*)d_ws;
        unsigned short* feat = fbf + fbf_elems;
        unsigned short* wb   = feat + feat_elems;

        wcvt_kernel<<<(NOUT * FEAT_DIM) / (256 * 4), 256, 0, stream>>>(lw, wb);
        fcvt_sliced<<<NUM_NODES / 16, 256, 0, stream>>>(features, fbf);
        agg_sliced<<<(NROWS / 64) * NSLICE, 256, 0, stream>>>(nodes, adj, fbf, feat);
        gemm_kernel<<<dim3(NROWS / 128, NOUT / 128), 256, 0, stream>>>(feat, wb, out);
    } else {
        unsigned short* feat = (unsigned short*)d_ws;
        unsigned short* wb   = feat + feat_elems;

        wcvt_kernel<<<(NOUT * FEAT_DIM) / (256 * 4), 256, 0, stream>>>(lw, wb);
        agg_f32_kernel<<<NROWS, 256, 0, stream>>>(nodes, adj, features, feat);
        gemm_kernel<<<dim3(NROWS / 128, NOUT / 128), 256, 0, stream>>>(feat, wb, out);
    }
}

// Round 4
// 78.157 us; speedup vs baseline: 2.4058x; 1.0014x over previous
//
#include <hip/hip_runtime.h>

#define FEAT_DIM 256
#define K_NEIGH  32
#define NROWS    20480   // B*S = 2048*10
#define NOUT     1024    // CLIPS*DIM = 8*128
#define NUM_NODES 50000
#define SLICE_DIM 32     // dims per XCD slice
#define NSLICE    8
#define FBLK      1563   // ceil(NUM_NODES/32)

typedef __attribute__((ext_vector_type(8))) short bf16x8;
typedef __attribute__((ext_vector_type(4))) float f32x4;

__device__ __forceinline__ unsigned short f2bf(float f) {
    unsigned int u = __builtin_bit_cast(unsigned int, f);
    u += 0x7fffu + ((u >> 16) & 1u);
    return (unsigned short)(u >> 16);
}
__device__ __forceinline__ float bf2f(unsigned short h) {
    unsigned int u = ((unsigned int)h) << 16;
    return __builtin_bit_cast(float, u);
}
__device__ __forceinline__ void gload16(const void* g, void* l) {
    __builtin_amdgcn_global_load_lds(
        (const __attribute__((address_space(1))) unsigned int*)g,
        (__attribute__((address_space(3))) unsigned int*)l, 16, 0, 0);
}

// ---- weight-only convert (fallback path) ------------------------------------
__global__ __launch_bounds__(256) void wcvt_kernel(const float* __restrict__ w,
                                                   unsigned short* __restrict__ wb) {
    int i = (blockIdx.x * 256 + threadIdx.x) * 4;
    float4 v = *(const float4*)(w + i);
    ushort4 o;
    o.x = f2bf(v.x); o.y = f2bf(v.y); o.z = f2bf(v.z); o.w = f2bf(v.w);
    *(ushort4*)(wb + i) = o;
}

// ---- convert: features -> sliced bf16 fb[8][50000][32]  +  W -> bf16 --------
__global__ __launch_bounds__(256) void cvt_kernel(const float* __restrict__ f,
                                                  unsigned short* __restrict__ fb,
                                                  const float* __restrict__ w,
                                                  unsigned short* __restrict__ wb) {
    int b = blockIdx.x;
    int t = threadIdx.x;
    if (b < FBLK) {
        int g = t >> 5;            // slice 0..7
        int i = t & 31;            // node offset
        int node = b * 32 + i;
        if (node >= NUM_NODES) return;
        const float* src = f + (long)node * FEAT_DIM + g * SLICE_DIM;   // full 128B line
        unsigned short o[32];
        #pragma unroll
        for (int j = 0; j < 32; j += 4) {
            float4 v = *(const float4*)(src + j);
            o[j] = f2bf(v.x); o[j+1] = f2bf(v.y); o[j+2] = f2bf(v.z); o[j+3] = f2bf(v.w);
        }
        unsigned short* dst = fb + ((long)g * NUM_NODES + node) * SLICE_DIM; // 64B/thr contiguous
        #pragma unroll
        for (int j = 0; j < 4; ++j)
            *(bf16x8*)(dst + j * 8) = *(const bf16x8*)(o + j * 8);
    } else {
        int i = ((b - FBLK) * 256 + t) * 4;
        float4 v = *(const float4*)(w + i);
        ushort4 o;
        o.x = f2bf(v.x); o.y = f2bf(v.y); o.z = f2bf(v.z); o.w = f2bf(v.w);
        *(ushort4*)(wb + i) = o;
    }
}

// ---- agg, XCD-sliced (adj reads same-address-coalesced) ---------------------
__global__ __launch_bounds__(256) void agg_sliced(const int* __restrict__ nodes,
                                                  const int* __restrict__ adj,
                                                  const unsigned short* __restrict__ fb,
                                                  unsigned short* __restrict__ feat) {
    int slice = blockIdx.x & 7;
    int chunk = blockIdx.x >> 3;
    int t = threadIdx.x;
    int row = chunk * 64 + (t >> 2);
    int d8 = (t & 3) * 8;
    int node = nodes[row];
    const int* arow = adj + (long)node * K_NEIGH;
    int nbr[K_NEIGH];
    #pragma unroll
    for (int kk = 0; kk < K_NEIGH / 4; ++kk)
        *(int4*)(nbr + kk * 4) = ((const int4*)arow)[kk];

    const unsigned short* base = fb + (long)slice * NUM_NODES * SLICE_DIM + d8;
    float acc[8] = {};
    #pragma unroll
    for (int k = 0; k < K_NEIGH; ++k) {
        bf16x8 v = *(const bf16x8*)(base + (long)nbr[k] * SLICE_DIM);
        #pragma unroll
        for (int j = 0; j < 8; ++j) acc[j] += bf2f((unsigned short)v[j]);
    }
    unsigned short o[8];
    #pragma unroll
    for (int j = 0; j < 8; ++j) o[j] = f2bf(acc[j] * (1.0f / K_NEIGH));
    *(bf16x8*)(feat + (long)row * FEAT_DIM + slice * SLICE_DIM + d8) = *(const bf16x8*)o;
}

// ---- agg from fp32 features (ws fallback) -----------------------------------
__global__ __launch_bounds__(256) void agg_f32_kernel(const int* __restrict__ nodes,
                                                      const int* __restrict__ adj,
                                                      const float* __restrict__ features,
                                                      unsigned short* __restrict__ feat) {
    int row = blockIdx.x;
    int t = threadIdx.x;
    int node = nodes[row];
    const int* arow = adj + (long)node * K_NEIGH;
    float acc = 0.f;
    #pragma unroll
    for (int k = 0; k < K_NEIGH; ++k) {
        long nb = arow[k];
        acc += features[nb * FEAT_DIM + t];
    }
    feat[(long)row * FEAT_DIM + t] = f2bf(acc * (1.0f / K_NEIGH));
}

// ---- GEMM: C = relu(feat x W^T), 128x128 tile, 2-phase double-buffered LDS --
__global__ __launch_bounds__(256) void gemm_kernel(const unsigned short* __restrict__ A,
                                                   const unsigned short* __restrict__ Bw,
                                                   float* __restrict__ C) {
    __shared__ short As[2][128 * 32];   // 16 KB
    __shared__ short Bs[2][128 * 32];   // 16 KB

    int t = threadIdx.x;
    int wave = t >> 6, lane = t & 63;
    int wm = wave >> 1, wn = wave & 1;
    int m0 = blockIdx.x * 128, n0 = blockIdx.y * 128;
    int lr = lane & 15;
    int lk = (lane >> 4) * 8;

    int srow = t >> 2;
    int sseg = (t & 3) * 8;
    const short* Ag = (const short*)A + (long)(m0 + srow) * FEAT_DIM + sseg;
    const short* Bg = (const short*)Bw + (long)(n0 + srow) * FEAT_DIM + sseg;

    f32x4 acc[4][4] = {};

#define STAGE(bufi, kb) do {                                         \
    gload16(Ag + (kb), &As[bufi][t * 8]);                            \
    gload16(Ag + 64 * FEAT_DIM + (kb), &As[bufi][64 * 32 + t * 8]);  \
    gload16(Bg + (kb), &Bs[bufi][t * 8]);                            \
    gload16(Bg + 64 * FEAT_DIM + (kb), &Bs[bufi][64 * 32 + t * 8]);  \
} while (0)

    STAGE(0, 0);
    asm volatile("s_waitcnt vmcnt(0)" ::: "memory");
    __builtin_amdgcn_s_barrier();

    #pragma unroll
    for (int it = 0; it < 8; ++it) {
        int cur = it & 1;
        if (it < 7) STAGE(cur ^ 1, (it + 1) * 32);   // next-tile loads fly under compute

        bf16x8 a[4], b[4];
        #pragma unroll
        for (int i = 0; i < 4; ++i)
            a[i] = *(const bf16x8*)(&As[cur][(wm * 64 + i * 16 + lr) * 32 + lk]);
        #pragma unroll
        for (int j = 0; j < 4; ++j)
            b[j] = *(const bf16x8*)(&Bs[cur][(wn * 64 + j * 16 + lr) * 32 + lk]);
        #pragma unroll
        for (int i = 0; i < 4; ++i)
            #pragma unroll
            for (int j = 0; j < 4; ++j)
                acc[i][j] = __builtin_amdgcn_mfma_f32_16x16x32_bf16(a[i], b[j], acc[i][j], 0, 0, 0);

        if (it < 7) {
            asm volatile("s_waitcnt vmcnt(0)" ::: "memory");  // next tile landed
            __builtin_amdgcn_s_barrier();                      // all readers of old buf done
        }
    }
#undef STAGE

    // C/D layout: col = lane&15, row = (lane>>4)*4 + reg  (verified R0)
    int crow0 = m0 + wm * 64 + (lane >> 4) * 4;
    int ccol0 = n0 + wn * 64 + lr;
    #pragma unroll
    for (int i = 0; i < 4; ++i)
        #pragma unroll
        for (int j = 0; j < 4; ++j)
            #pragma unroll
            for (int r = 0; r < 4; ++r) {
                float v = acc[i][j][r];
                C[(long)(crow0 + i * 16 + r) * NOUT + ccol0 + j * 16] = v > 0.f ? v : 0.f;
            }
}

extern "C" void kernel_launch(void* const* d_in, const int* in_sizes, int n_in,
                              void* d_out, int out_size, void* d_ws, size_t ws_size,
                              hipStream_t stream) {
    const int*   nodes    = (const int*)d_in[0];
    const int*   adj      = (const int*)d_in[1];
    const float* features = (const float*)d_in[2];
    const float* lw       = (const float*)d_in[3];
    float*       out      = (float*)d_out;

    const size_t fbf_elems  = (size_t)NUM_NODES * FEAT_DIM;
    const size_t feat_elems = (size_t)NROWS * FEAT_DIM;
    const size_t need = (fbf_elems + feat_elems + (size_t)NOUT * FEAT_DIM) * 2;

    if (ws_size >= need) {
        unsigned short* fbf  = (unsigned short*)d_ws;
        unsigned short* feat = fbf + fbf_elems;
        unsigned short* wb   = feat + feat_elems;

        cvt_kernel<<<FBLK + (NOUT * FEAT_DIM) / (256 * 4), 256, 0, stream>>>(features, fbf, lw, wb);
        agg_sliced<<<(NROWS / 64) * NSLICE, 256, 0, stream>>>(nodes, adj, fbf, feat);
        gemm_kernel<<<dim3(NROWS / 128, NOUT / 128), 256, 0, stream>>>(feat, wb, out);
    } else {
        unsigned short* feat = (unsigned short*)d_ws;
        unsigned short* wb   = feat + feat_elems;

        wcvt_kernel<<<(NOUT * FEAT_DIM) / (256 * 4), 256, 0, stream>>>(lw, wb);
        agg_f32_kernel<<<NROWS, 256, 0, stream>>>(nodes, adj, features, feat);
        gemm_kernel<<<dim3(NROWS / 128, NOUT / 128), 256, 0, stream>>>(feat, wb, out);
    }
}